// Round 1
// baseline (605.150 us; speedup 1.0000x reference)
//
#include <hip/hip_runtime.h>
#include <hip/hip_bf16.h>
#include <math.h>

#define QQ   10
#define CC   64
#define HWSZ 65536          // H*W
#define NPOS 655360         // Q*H*W
#define LL   64800          // L_H*L_W
#define KK   9

// ---------------------------------------------------------------------------
// Kernel 1: transpose x (bq, c, hw) -> xt (b, n, c)  [n = q*HW + hw]
//           fused with per-n channel sum & max (for attention stats).
// Grid: (1024, 20) blocks of 256 threads. Each block: 64(hw) x 64(c) tile.
// ---------------------------------------------------------------------------
__global__ __launch_bounds__(256) void k_transpose_stats(
    const float* __restrict__ x, float* __restrict__ xt,
    float* __restrict__ s, float* __restrict__ m) {
  __shared__ float tile[64][65];   // [c][hw], +1 pad -> conflict-free column read
  const int t    = threadIdx.x;
  const int lane = t & 63;
  const int wid  = t >> 6;
  const int hw_base = blockIdx.x * 64;
  const int bq = blockIdx.y;            // 0..19
  const float* xp = x + (size_t)bq * CC * HWSZ + hw_base;

  // Load 64x64 tile, float4 per thread x4 (coalesced 16B/lane)
#pragma unroll
  for (int i = 0; i < 4; ++i) {
    int linear = t + i * 256;           // 0..1023
    int row  = linear >> 4;             // channel
    int col4 = (linear & 15) << 2;      // hw offset within tile
    const float4 v = *(const float4*)(xp + (size_t)row * HWSZ + col4);
    tile[row][col4 + 0] = v.x;
    tile[row][col4 + 1] = v.y;
    tile[row][col4 + 2] = v.z;
    tile[row][col4 + 3] = v.w;
  }
  __syncthreads();

  const int b = bq / QQ, q = bq % QQ;
  const size_t n_base = (size_t)q * HWSZ + hw_base;
  float* xtb = xt + (size_t)b * NPOS * CC;
  float* sb  = s  + (size_t)b * NPOS;
  float* mb  = m  + (size_t)b * NPOS;

  // Each wave handles 16 positions: lane = channel, coalesced 256B writes.
#pragma unroll 4
  for (int i = 0; i < 16; ++i) {
    const int nl = wid * 16 + i;
    float v = tile[lane][nl];           // bank = lane%32 -> 2 lanes/bank (free)
    float sum = v, mx = v;
#pragma unroll
    for (int off = 32; off; off >>= 1) {
      sum += __shfl_xor(sum, off);
      mx = fmaxf(mx, __shfl_xor(mx, off));
    }
    const size_t n = n_base + nl;
    xtb[n * CC + lane] = v;
    if (lane == 0) { sb[n] = sum; mb[n] = mx; }
  }
}

// ---------------------------------------------------------------------------
// Kernel 2: per (b,l): gather stats -> sigmoid attention -> weighted channel
//           reduction from xt (coalesced 256B gathers) -> out (b,c,l).
// Block = 256 threads = 4 waves; each wave does 4 l's; block covers 16 l's.
// Grid: 2 * (64800/16) = 8100 blocks, b-major so each b's 168MB xt slice
// enjoys LLC residency.
// ---------------------------------------------------------------------------
__global__ __launch_bounds__(256) void k_gather_out(
    const float* __restrict__ xt, const float* __restrict__ s,
    const float* __restrict__ m, const int* __restrict__ idx,
    const float* __restrict__ att_w, const float* __restrict__ att_b,
    const float* __restrict__ tc_w, const float* __restrict__ tc_b,
    float* __restrict__ out) {
  const int blk    = blockIdx.x;
  const int b      = blk / (LL / 16);
  const int l_base = (blk % (LL / 16)) * 16;
  const int t = threadIdx.x, lane = t & 63, wid = t >> 6;
  __shared__ float res[64][17];        // [c][l-within-block], padded

  // Per-lane (=channel) weights
  float tcw[KK];
#pragma unroll
  for (int k = 0; k < KK; ++k) tcw[k] = tc_w[lane * KK + k];
  const float tcb = tc_b[lane];

  // Attention params: lanes 0..8 are the 9 output heads (clamped for others)
  const int c9 = lane < KK ? lane : 0;
  float aw0[KK], aw1[KK];
#pragma unroll
  for (int k = 0; k < KK; ++k) {
    aw0[k] = att_w[c9 * 2 * KK + k];
    aw1[k] = att_w[c9 * 2 * KK + KK + k];
  }
  const float ab = att_b[c9];

  const float* xtb = xt + (size_t)b * NPOS * CC;
  const float* sb  = s  + (size_t)b * NPOS;
  const float* mb  = m  + (size_t)b * NPOS;

#pragma unroll
  for (int j = 0; j < 4; ++j) {
    const int l = l_base + wid * 4 + j;
    // lanes 0..8 fetch idx + stats (others load lane 8's copy: broadcast, free)
    const int kl = lane < KK ? lane : KK - 1;
    const int nk = idx[l * KK + kl];
    const float sv = sb[nk];
    const float mv = mb[nk];

    // 9 attention logits (lanes 0..8 meaningful; all lanes compute)
    float logit = ab;
#pragma unroll
    for (int k = 0; k < KK; ++k) {
      const float mean = __shfl(sv, k) * (1.0f / 64.0f);
      const float mx   = __shfl(mv, k);
      logit = fmaf(mean, aw0[k], logit);
      logit = fmaf(mx,   aw1[k], logit);
    }
    const float w = 1.0f + 1.0f / (1.0f + __expf(-logit));

    // Weighted gather-reduce over k: each gather = 64 lanes x 4B contiguous
    float acc = 0.0f;
#pragma unroll
    for (int k = 0; k < KK; ++k) {
      const int   n  = __shfl(nk, k);
      const float wk = __shfl(w, k);
      const float v  = xtb[(size_t)n * CC + lane];
      acc = fmaf(wk * tcw[k], v, acc);
    }
    res[lane][wid * 4 + j] = acc + tcb;
  }
  __syncthreads();

  // Coalesced output: thread t -> c = t/4, 4 consecutive l; 64B/line fully
  // written by 4 lanes; float4 aligned (l_base % 16 == 0).
  const int c  = t >> 2;
  const int j4 = t & 3;
  float4 o;
  o.x = res[c][j4 * 4 + 0];
  o.y = res[c][j4 * 4 + 1];
  o.z = res[c][j4 * 4 + 2];
  o.w = res[c][j4 * 4 + 3];
  *(float4*)(out + ((size_t)b * CC + c) * LL + l_base + j4 * 4) = o;
}

extern "C" void kernel_launch(void* const* d_in, const int* in_sizes, int n_in,
                              void* d_out, int out_size, void* d_ws, size_t ws_size,
                              hipStream_t stream) {
  const float* x     = (const float*)d_in[0];
  const int*   idx   = (const int*)d_in[1];
  const float* att_w = (const float*)d_in[2];
  const float* att_b = (const float*)d_in[3];
  const float* tc_w  = (const float*)d_in[4];
  const float* tc_b  = (const float*)d_in[5];
  float* out = (float*)d_out;

  // Workspace carve-up: xt (2*N*64 f32) | s (2*N) | m (2*N)  ~= 346 MB
  float* xt = (float*)d_ws;
  float* s  = xt + (size_t)2 * NPOS * CC;
  float* mm = s + (size_t)2 * NPOS;

  dim3 g1(HWSZ / 64, 2 * QQ);
  k_transpose_stats<<<g1, 256, 0, stream>>>(x, xt, s, mm);

  dim3 g2(2 * (LL / 16));
  k_gather_out<<<g2, 256, 0, stream>>>(xt, s, mm, idx, att_w, att_b,
                                       tc_w, tc_b, out);
}

// Round 2
// 534.787 us; speedup vs baseline: 1.1316x; 1.1316x over previous
//
#include <hip/hip_runtime.h>
#include <hip/hip_bf16.h>
#include <math.h>

#define QQ   10
#define CC   64
#define HWSZ 65536          // H*W
#define NPOS 655360         // Q*H*W
#define LL   64800          // L_H*L_W
#define KK   9

// ---------------------------------------------------------------------------
// Kernel 1: transpose x (bq, c, hw) -> xt (b, n, c) in BF16  [n = q*HW + hw]
//           fused with per-n channel sum & max (fp32) for attention stats.
// Grid: (1024, 20) blocks of 256 threads. Each block: 64(hw) x 64(c) tile.
// ---------------------------------------------------------------------------
__global__ __launch_bounds__(256) void k_transpose_stats(
    const float* __restrict__ x, __hip_bfloat16* __restrict__ xt,
    float* __restrict__ s, float* __restrict__ m) {
  __shared__ float tile[64][65];   // [c][hw], +1 pad -> conflict-free col reads
  __shared__ float sred[4][64];
  __shared__ float mred[4][64];
  const int t    = threadIdx.x;
  const int lane = t & 63;
  const int wid  = t >> 6;
  const int hw_base = blockIdx.x * 64;
  const int bq = blockIdx.y;            // 0..19
  const float* xp = x + (size_t)bq * CC * HWSZ + hw_base;

  // Load 64x64 tile, float4 per thread x4 (coalesced 16B/lane)
#pragma unroll
  for (int i = 0; i < 4; ++i) {
    int linear = t + i * 256;           // 0..1023
    int row  = linear >> 4;             // channel
    int col4 = (linear & 15) << 2;      // hw offset within tile
    const float4 v = *(const float4*)(xp + (size_t)row * HWSZ + col4);
    tile[row][col4 + 0] = v.x;
    tile[row][col4 + 1] = v.y;
    tile[row][col4 + 2] = v.z;
    tile[row][col4 + 3] = v.w;
  }
  __syncthreads();

  const int b = bq / QQ, q = bq % QQ;
  const size_t n_base = (size_t)q * HWSZ + hw_base;
  __hip_bfloat16* xtb = xt + (size_t)b * NPOS * CC;
  float* sb  = s  + (size_t)b * NPOS;
  float* mb  = m  + (size_t)b * NPOS;

  // Phase A: transposed bf16 store. Each wave: lane = channel, 16 positions;
  // 64 lanes x 2B = 128 B contiguous per store.
#pragma unroll 4
  for (int i = 0; i < 16; ++i) {
    const int nl = wid * 16 + i;
    const size_t n = n_base + nl;
    xtb[n * CC + lane] = __float2bfloat16(tile[lane][nl]);
  }

  // Phase B: per-position channel sum/max. Thread t: position = t&63,
  // channels [wid*16, wid*16+16). LDS reads 2-way aliased (free).
  {
    const int pos = lane;
    const int c0  = wid * 16;
    float psum = tile[c0][pos];
    float pmax = psum;
#pragma unroll
    for (int c = 1; c < 16; ++c) {
      const float v = tile[c0 + c][pos];
      psum += v;
      pmax = fmaxf(pmax, v);
    }
    sred[wid][pos] = psum;
    mred[wid][pos] = pmax;
  }
  __syncthreads();
  if (wid == 0) {
    const int pos = lane;
    const float sum = sred[0][pos] + sred[1][pos] + sred[2][pos] + sred[3][pos];
    const float mx  = fmaxf(fmaxf(mred[0][pos], mred[1][pos]),
                            fmaxf(mred[2][pos], mred[3][pos]));
    sb[n_base + pos] = sum;
    mb[n_base + pos] = mx;
  }
}

// ---------------------------------------------------------------------------
// Kernel 2: per (b,l): gather stats -> sigmoid attention -> weighted channel
//           reduction from bf16 xt (coalesced 128B gathers) -> out (b,c,l).
// Block = 256 threads = 4 waves; each wave does 4 l's; block covers 16 l's.
// Grid b-major so each b's 168MB xt slice enjoys LLC residency.
// ---------------------------------------------------------------------------
__global__ __launch_bounds__(256) void k_gather_out(
    const __hip_bfloat16* __restrict__ xt, const float* __restrict__ s,
    const float* __restrict__ m, const int* __restrict__ idx,
    const float* __restrict__ att_w, const float* __restrict__ att_b,
    const float* __restrict__ tc_w, const float* __restrict__ tc_b,
    float* __restrict__ out) {
  const int blk    = blockIdx.x;
  const int b      = blk / (LL / 16);
  const int l_base = (blk % (LL / 16)) * 16;
  const int t = threadIdx.x, lane = t & 63, wid = t >> 6;
  __shared__ float res[64][17];        // [c][l-within-block], padded

  // Per-lane (=channel) weights
  float tcw[KK];
#pragma unroll
  for (int k = 0; k < KK; ++k) tcw[k] = tc_w[lane * KK + k];
  const float tcb = tc_b[lane];

  // Attention params: lanes 0..8 are the 9 output heads (clamped for others)
  const int c9 = lane < KK ? lane : 0;
  float aw0[KK], aw1[KK];
#pragma unroll
  for (int k = 0; k < KK; ++k) {
    aw0[k] = att_w[c9 * 2 * KK + k];
    aw1[k] = att_w[c9 * 2 * KK + KK + k];
  }
  const float ab = att_b[c9];

  const __hip_bfloat16* xtb = xt + (size_t)b * NPOS * CC;
  const float* sb  = s  + (size_t)b * NPOS;
  const float* mb  = m  + (size_t)b * NPOS;

#pragma unroll
  for (int j = 0; j < 4; ++j) {
    const int l = l_base + wid * 4 + j;
    // lanes 0..8 fetch idx + stats (others duplicate lane 8: broadcast, free)
    const int kl = lane < KK ? lane : KK - 1;
    const int nk = idx[l * KK + kl];
    const float sv = sb[nk];
    const float mv = mb[nk];

    // 9 attention logits (lanes 0..8 meaningful; all lanes compute)
    float logit = ab;
#pragma unroll
    for (int k = 0; k < KK; ++k) {
      const float mean = __shfl(sv, k) * (1.0f / 64.0f);
      const float mx   = __shfl(mv, k);
      logit = fmaf(mean, aw0[k], logit);
      logit = fmaf(mx,   aw1[k], logit);
    }
    const float w = 1.0f + 1.0f / (1.0f + __expf(-logit));

    // Weighted gather-reduce over k: each gather = 64 lanes x 2B contiguous
    float acc = 0.0f;
#pragma unroll
    for (int k = 0; k < KK; ++k) {
      const int   n  = __shfl(nk, k);
      const float wk = __shfl(w, k);
      const float v  = __bfloat162float(xtb[(size_t)n * CC + lane]);
      acc = fmaf(wk * tcw[k], v, acc);
    }
    res[lane][wid * 4 + j] = acc + tcb;
  }
  __syncthreads();

  // Coalesced output: thread t -> c = t/4, 4 consecutive l; float4 aligned.
  const int c  = t >> 2;
  const int j4 = t & 3;
  float4 o;
  o.x = res[c][j4 * 4 + 0];
  o.y = res[c][j4 * 4 + 1];
  o.z = res[c][j4 * 4 + 2];
  o.w = res[c][j4 * 4 + 3];
  *(float4*)(out + ((size_t)b * CC + c) * LL + l_base + j4 * 4) = o;
}

extern "C" void kernel_launch(void* const* d_in, const int* in_sizes, int n_in,
                              void* d_out, int out_size, void* d_ws, size_t ws_size,
                              hipStream_t stream) {
  const float* x     = (const float*)d_in[0];
  const int*   idx   = (const int*)d_in[1];
  const float* att_w = (const float*)d_in[2];
  const float* att_b = (const float*)d_in[3];
  const float* tc_w  = (const float*)d_in[4];
  const float* tc_b  = (const float*)d_in[5];
  float* out = (float*)d_out;

  // Workspace carve-up: xt bf16 (2*N*64) | s (2*N f32) | m (2*N f32) ~= 178 MB
  __hip_bfloat16* xt = (__hip_bfloat16*)d_ws;
  float* s  = (float*)(xt + (size_t)2 * NPOS * CC);
  float* mm = s + (size_t)2 * NPOS;

  dim3 g1(HWSZ / 64, 2 * QQ);
  k_transpose_stats<<<g1, 256, 0, stream>>>(x, xt, s, mm);

  dim3 g2(2 * (LL / 16));
  k_gather_out<<<g2, 256, 0, stream>>>(xt, s, mm, idx, att_w, att_b,
                                       tc_w, tc_b, out);
}